// Round 4
// baseline (525.284 us; speedup 1.0000x reference)
//
#include <hip/hip_runtime.h>

typedef __bf16 bf16x8 __attribute__((ext_vector_type(8)));
typedef __bf16 bf16x4 __attribute__((ext_vector_type(4)));
typedef float floatx4 __attribute__((ext_vector_type(4)));

__device__ __forceinline__ __bf16 f2bf(float f) {
  union { float f; unsigned u; } x; x.f = f;
  unsigned r = (x.u + 0x7FFFu + ((x.u >> 16) & 1u)) >> 16;
  union { unsigned short u; __bf16 b; } o; o.u = (unsigned short)r; return o.b;
}
__device__ __forceinline__ float bf2f(__bf16 b) {
  union { unsigned short u; __bf16 b; } i; i.b = b;
  union { unsigned u; float f; } y; y.u = ((unsigned)i.u) << 16; return y.f;
}
__device__ __forceinline__ bf16x8 cvt8(float4 f0, float4 f1) {
  bf16x8 v;
  v[0] = f2bf(f0.x); v[1] = f2bf(f0.y); v[2] = f2bf(f0.z); v[3] = f2bf(f0.w);
  v[4] = f2bf(f1.x); v[5] = f2bf(f1.y); v[6] = f2bf(f1.z); v[7] = f2bf(f1.w);
  return v;
}

// Byte offset of element (row,col) in a fragment-major tile with Kb = K/32
// k-blocks: granule (16B) holds rows of one (mt,kk32,quad) fragment slice.
// Reads for MFMA are then base + blk*1024 + lane*16 (contiguous, conflict-free).
__device__ __forceinline__ int afoff(int row, int col, int Kb) {
  return ((((row >> 4) * Kb + (col >> 5)) * 64 + ((col >> 3) & 3) * 16 + (row & 15)) << 4)
         + ((col & 7) << 1);
}

#define MFMA16(a, b, c) __builtin_amdgcn_mfma_f32_16x16x32_bf16(a, b, c, 0, 0, 0)

// ---------------- prep: weights -> FRAGMENT-MAJOR bf16 layout ----------------
// Element (nt, kk32, lane, e) = W[k = kk32*32 + (lane>>4)*8 + e][n = nt*16 + (lane&15)].
__global__ __launch_bounds__(256) void prep_weights(
    const float* __restrict__ W1, const float* __restrict__ WQ,
    const float* __restrict__ WK, const float* __restrict__ WV,
    const float* __restrict__ W2,
    __bf16* __restrict__ w1f, __bf16* __restrict__ wqf,
    __bf16* __restrict__ wkf, __bf16* __restrict__ wvf,
    __bf16* __restrict__ w2f) {
  int i = blockIdx.x * 256 + threadIdx.x;
  if (i < 147456) {  // W1: K=768 (kk32 0..23), N=192 (nt 0..11)
    int e = i & 7, lane = (i >> 3) & 63, rest = i >> 9;
    int kk32 = rest % 24, nt = rest / 24;
    int n = nt * 16 + (lane & 15), k = kk32 * 32 + (lane >> 4) * 8 + e;
    w1f[i] = f2bf(W1[k * 192 + n]); return;
  }
  i -= 147456;
  if (i < 36864) {   // WQ: K=192, N=192
    int e = i & 7, lane = (i >> 3) & 63, rest = i >> 9;
    int kk32 = rest % 6, nt = rest / 6;
    int n = nt * 16 + (lane & 15), k = kk32 * 32 + (lane >> 4) * 8 + e;
    wqf[i] = f2bf(WQ[k * 192 + n]); return;
  }
  i -= 36864;
  if (i < 36864) {
    int e = i & 7, lane = (i >> 3) & 63, rest = i >> 9;
    int kk32 = rest % 6, nt = rest / 6;
    int n = nt * 16 + (lane & 15), k = kk32 * 32 + (lane >> 4) * 8 + e;
    wkf[i] = f2bf(WK[k * 192 + n]); return;
  }
  i -= 36864;
  if (i < 36864) {
    int e = i & 7, lane = (i >> 3) & 63, rest = i >> 9;
    int kk32 = rest % 6, nt = rest / 6;
    int n = nt * 16 + (lane & 15), k = kk32 * 32 + (lane >> 4) * 8 + e;
    wvf[i] = f2bf(WV[k * 192 + n]); return;
  }
  i -= 36864;
  if (i < 147456) {  // W2: K=192 (kk32 0..5), N=768 (nt 0..47)
    int e = i & 7, lane = (i >> 3) & 63, rest = i >> 9;
    int kk32 = rest % 6, nt = rest / 6;
    int n = nt * 16 + (lane & 15), k = kk32 * 32 + (lane >> 4) * 8 + e;
    w2f[i] = f2bf(W2[k * 768 + n]); return;
  }
}

// xpos tables: [32][192] each (repeat-2 applied)
__global__ __launch_bounds__(256) void prep_tables(
    float* __restrict__ cq, float* __restrict__ sq,
    float* __restrict__ ck, float* __restrict__ sk) {
  int i = blockIdx.x * 256 + threadIdx.x;
  if (i >= 32 * 96) return;
  int s = i / 96, f = i % 96;
  float base = (2.f * f + 0.4f * 192.f) / (1.4f * 192.f);
  float scale = powf(base, (float)s / 512.f);
  float invf = powf(10000.f, -(float)f / 96.f);
  float ang = (float)s * invf;
  float sn = sinf(ang), cs = cosf(ang);
  int o = s * 192 + 2 * f;
  cq[o] = cs * scale; cq[o + 1] = cs * scale;
  sq[o] = sn * scale; sq[o + 1] = sn * scale;
  ck[o] = cs / scale; ck[o + 1] = cs / scale;
  sk[o] = sn / scale; sk[o + 1] = sn / scale;
}

// ---------------- main fused kernel: one WG (4 waves) per 32-token sequence ----------------
// All LDS tiles fragment-major; all MFMA-feed reads are base+blk*1024+lane*16.
// x staged via double-buffered 32x192 chunks in the (dead-during-P1) Q/K regions.
__global__ __launch_bounds__(256, 3) void retnet_main(
    const float* __restrict__ x, const float* __restrict__ b1,
    const float* __restrict__ b2, const float* __restrict__ ln_g,
    const float* __restrict__ ln_b,
    const __bf16* __restrict__ w1f, const __bf16* __restrict__ wqf,
    const __bf16* __restrict__ wkf, const __bf16* __restrict__ wvf,
    const __bf16* __restrict__ w2f,
    const float* __restrict__ cq, const float* __restrict__ sq,
    const float* __restrict__ ck, const float* __restrict__ sk,
    float* __restrict__ out) {
  // LDS 49152 B -> 3 blocks/CU:
  //   Qb  @     0 (12288)  P1: staging bufA | P3/P4: Q | after P4: att (first 2048)
  //   Kb  @ 12288 (12288)  P1: staging bufB | P3/P4: K
  //   Vtb @ 24576 (12288)  V as B-frags ([d-tile][lane][8 s-elems])
  //   hb  @ 36864 (12288)  h | after P5: ret
  __shared__ __align__(16) char smem[49152];
  char* Qb = smem;
  char* Kb = smem + 12288;
  char* Vtb = smem + 24576;
  char* hb = smem + 36864;

  const int tid = threadIdx.x;
  const int wv = tid >> 6;      // 0..3
  const int lane = tid & 63;
  const int l16 = lane & 15;
  const int quad = lane >> 4;
  const int lane16 = lane << 4; // byte offset within a 1024B fragment block
  const int wv3 = wv * 3;
  const int p = blockIdx.x;
  const float* xblk = x + (size_t)p * 24576;

  // Staging geometry: thread owns row srow, 8-col group scol8 in each 64-col third.
  const int srow = tid >> 3;
  const int scol8 = (tid & 7) * 8;
  const float* sbase = xblk + srow * 768 + scol8;
  const int wo0 = ((((srow >> 4) * 6 + (scol8 >> 5)) * 64 +
                    ((scol8 >> 3) & 3) * 16 + (srow & 15)) << 4);
  const char* w1b = (const char*)w1f;

  // ---- Phase 1: x_down = xr @ W1 + b1 (M=32,N=192,K=768) -> h ----
  floatx4 acc[2][3] = {};
  {
    // prologue: stage chunk 0 (cols 0..191) into Qb
    {
      float4 L[6];
#pragma unroll
      for (int g = 0; g < 3; ++g) {
        const float* a = sbase + g * 64;
        L[2 * g] = *(const float4*)a; L[2 * g + 1] = *(const float4*)(a + 4);
      }
#pragma unroll
      for (int g = 0; g < 3; ++g)
        *(bf16x8*)(Qb + wo0 + g * 2048) = cvt8(L[2 * g], L[2 * g + 1]);
    }
    __syncthreads();
#pragma unroll
    for (int c = 0; c < 4; ++c) {
      char* rb = (c & 1) ? Kb : Qb;
      char* wb = (c & 1) ? Qb : Kb;
      float4 L[6];
      if (c < 3) {  // issue next chunk's global loads early
#pragma unroll
        for (int g = 0; g < 3; ++g) {
          const float* a = sbase + (c + 1) * 192 + g * 64;
          L[2 * g] = *(const float4*)a; L[2 * g + 1] = *(const float4*)(a + 4);
        }
      }
#pragma unroll
      for (int kkc = 0; kkc < 6; ++kkc) {
        bf16x8 a0 = *(const bf16x8*)(rb + kkc * 1024 + lane16);
        bf16x8 a1 = *(const bf16x8*)(rb + (6 + kkc) * 1024 + lane16);
#pragma unroll
        for (int t = 0; t < 3; ++t) {
          bf16x8 bb = *(const bf16x8*)(w1b + (size_t)((wv3 + t) * 24 + c * 6 + kkc) * 1024 + lane16);
          acc[0][t] = MFMA16(a0, bb, acc[0][t]);
          acc[1][t] = MFMA16(a1, bb, acc[1][t]);
        }
      }
      if (c < 3) {
#pragma unroll
        for (int g = 0; g < 3; ++g)
          *(bf16x8*)(wb + wo0 + g * 2048) = cvt8(L[2 * g], L[2 * g + 1]);
        __syncthreads();
      }
    }
    // epilogue -> h (fragment-major scalar writes)
#pragma unroll
    for (int m = 0; m < 2; ++m)
#pragma unroll
      for (int t = 0; t < 3; ++t) {
        int col = wv * 48 + t * 16 + l16;
        float bias = b1[col];
#pragma unroll
        for (int r = 0; r < 4; ++r) {
          int row = m * 16 + quad * 4 + r;
          *(__bf16*)(hb + afoff(row, col, 6)) = f2bf(acc[m][t][r] + bias);
        }
      }
  }
  __syncthreads();

  // ---- Phase 2: LayerNorm rows of h in place (8 lanes/row, 24 elems each) ----
  {
    int r = tid >> 3, g = tid & 7;
    float vals[24]; float s = 0.f, s2 = 0.f;
#pragma unroll
    for (int j = 0; j < 24; ++j) {
      int c = g * 24 + j;
      float v = bf2f(*(const __bf16*)(hb + afoff(r, c, 6)));
      vals[j] = v; s += v; s2 += v * v;
    }
#pragma unroll
    for (int o = 1; o < 8; o <<= 1) { s += __shfl_xor(s, o); s2 += __shfl_xor(s2, o); }
    float mu = s * (1.f / 192.f);
    float var = s2 * (1.f / 192.f) - mu * mu;
    float rstd = rsqrtf(var + 1e-5f);
#pragma unroll
    for (int j = 0; j < 24; ++j) {
      int c = g * 24 + j;
      *(__bf16*)(hb + afoff(r, c, 6)) = f2bf((vals[j] - mu) * rstd * ln_g[c] + ln_b[c]);
    }
  }
  __syncthreads();

  // ---- Phase 3: Q/K/V = h @ W; xpos on Q,K; V stored as B-frags ----
  auto gemm_h = [&](const __bf16* __restrict__ Wf, floatx4(&a)[2][3]) {
    const char* wc = (const char*)Wf;
#pragma unroll
    for (int kk = 0; kk < 6; ++kk) {
      bf16x8 a0 = *(const bf16x8*)(hb + kk * 1024 + lane16);
      bf16x8 a1 = *(const bf16x8*)(hb + (6 + kk) * 1024 + lane16);
#pragma unroll
      for (int t = 0; t < 3; ++t) {
        bf16x8 bb = *(const bf16x8*)(wc + (size_t)((wv3 + t) * 6 + kk) * 1024 + lane16);
        a[0][t] = MFMA16(a0, bb, a[0][t]);
        a[1][t] = MFMA16(a1, bb, a[1][t]);
      }
    }
  };
  {
    floatx4 aq[2][3] = {};
    gemm_h(wqf, aq);
#pragma unroll
    for (int m = 0; m < 2; ++m)
#pragma unroll
      for (int t = 0; t < 3; ++t) {
        int col = wv * 48 + t * 16 + l16;
#pragma unroll
        for (int r = 0; r < 4; ++r) {
          int row = m * 16 + quad * 4 + r;
          float v = aq[m][t][r];
          float pr = __shfl_xor(v, 1);
          float o = v * cq[row * 192 + col] + ((lane & 1) ? pr : -pr) * sq[row * 192 + col];
          *(__bf16*)(Qb + afoff(row, col, 6)) = f2bf(o);
        }
      }
  }
  {
    floatx4 ak[2][3] = {};
    gemm_h(wkf, ak);
#pragma unroll
    for (int m = 0; m < 2; ++m)
#pragma unroll
      for (int t = 0; t < 3; ++t) {
        int col = wv * 48 + t * 16 + l16;
#pragma unroll
        for (int r = 0; r < 4; ++r) {
          int row = m * 16 + quad * 4 + r;
          float v = ak[m][t][r];
          float pr = __shfl_xor(v, 1);
          float o = v * ck[row * 192 + col] + ((lane & 1) ? pr : -pr) * sk[row * 192 + col];
          *(__bf16*)(Kb + afoff(row, col, 6)) = f2bf(o);
        }
      }
  }
  {
    floatx4 av[2][3] = {};
    gemm_h(wvf, av);
#pragma unroll
    for (int m = 0; m < 2; ++m)
#pragma unroll
      for (int t = 0; t < 3; ++t) {
        int d = wv * 48 + t * 16 + l16;
        int s0 = m * 16 + quad * 4;
        bf16x4 pk;
#pragma unroll
        for (int r = 0; r < 4; ++r) pk[r] = f2bf(av[m][t][r]);
        *(bf16x4*)(Vtb + afoff(d, s0, 1)) = pk;  // B-frag: [d-tile][lane][8 s]
      }
  }
  __syncthreads();

  // ---- Phase 4: att = (Q @ K^T) * decay (32x32); one 16x16 tile per wave ----
  {
    int mt = wv >> 1, nt = wv & 1;
    floatx4 a4 = {0.f, 0.f, 0.f, 0.f};
#pragma unroll
    for (int kk = 0; kk < 6; ++kk) {
      bf16x8 a = *(const bf16x8*)(Qb + (mt * 6 + kk) * 1024 + lane16);
      bf16x8 bb = *(const bf16x8*)(Kb + (nt * 6 + kk) * 1024 + lane16);
      a4 = MFMA16(a, bb, a4);
    }
    __syncthreads();  // all Q/K reads done -> att may overwrite Qb
#pragma unroll
    for (int r = 0; r < 4; ++r) {
      int i = mt * 16 + quad * 4 + r;
      int j = nt * 16 + l16;
      float v = (i >= j) ? a4[r] * exp2f((float)(j - i)) : 0.f;
      *(__bf16*)(Qb + afoff(i, j, 1)) = f2bf(v);
    }
  }
  __syncthreads();

  // ---- Phase 5: ret = att @ V (M=32,N=192,K=32) -> hb (h is dead) ----
  {
    floatx4 ar[2][3] = {};
    bf16x8 a0 = *(const bf16x8*)(Qb + lane16);         // att mt=0
    bf16x8 a1 = *(const bf16x8*)(Qb + 1024 + lane16);  // att mt=1
#pragma unroll
    for (int t = 0; t < 3; ++t) {
      bf16x8 bb = *(const bf16x8*)(Vtb + (wv3 + t) * 1024 + lane16);
      ar[0][t] = MFMA16(a0, bb, ar[0][t]);
      ar[1][t] = MFMA16(a1, bb, ar[1][t]);
    }
#pragma unroll
    for (int m = 0; m < 2; ++m)
#pragma unroll
      for (int t = 0; t < 3; ++t) {
        int col = wv * 48 + t * 16 + l16;
#pragma unroll
        for (int r = 0; r < 4; ++r) {
          int row = m * 16 + quad * 4 + r;
          *(__bf16*)(hb + afoff(row, col, 6)) = f2bf(ar[m][t][r]);  // ret
        }
      }
  }
  __syncthreads();

  // ---- Phase 6: out = x + ret @ W2 + b2 (M=32,N=768,K=192) ----
  {
    const char* w2b = (const char*)w2f;
    bf16x8 af[2][6];
#pragma unroll
    for (int k6 = 0; k6 < 6; ++k6) {
      af[0][k6] = *(const bf16x8*)(hb + k6 * 1024 + lane16);
      af[1][k6] = *(const bf16x8*)(hb + (6 + k6) * 1024 + lane16);
    }
#pragma unroll
    for (int g = 0; g < 4; ++g) {
      floatx4 ao[2][3] = {};
#pragma unroll
      for (int k6 = 0; k6 < 6; ++k6) {
#pragma unroll
        for (int t = 0; t < 3; ++t) {
          bf16x8 bb = *(const bf16x8*)(w2b + (size_t)((wv * 12 + g * 3 + t) * 6 + k6) * 1024 + lane16);
          ao[0][t] = MFMA16(af[0][k6], bb, ao[0][t]);
          ao[1][t] = MFMA16(af[1][k6], bb, ao[1][t]);
        }
      }
#pragma unroll
      for (int m = 0; m < 2; ++m)
#pragma unroll
        for (int t = 0; t < 3; ++t) {
          int col = wv * 192 + g * 48 + t * 16 + l16;
          float bias = b2[col];
#pragma unroll
          for (int r = 0; r < 4; ++r) {
            int row = m * 16 + quad * 4 + r;
            size_t gi = (size_t)p * 24576 + row * 768 + col;
            out[gi] = xblk[row * 768 + col] + ao[m][t][r] + bias;
          }
        }
    }
  }
}

extern "C" void kernel_launch(void* const* d_in, const int* in_sizes, int n_in,
                              void* d_out, int out_size, void* d_ws, size_t ws_size,
                              hipStream_t stream) {
  const float* x = (const float*)d_in[0];
  const float* W1 = (const float*)d_in[1];
  const float* b1 = (const float*)d_in[2];
  const float* W2 = (const float*)d_in[3];
  const float* b2 = (const float*)d_in[4];
  const float* lng = (const float*)d_in[5];
  const float* lnb = (const float*)d_in[6];
  const float* WQ = (const float*)d_in[7];
  const float* WK = (const float*)d_in[8];
  const float* WV = (const float*)d_in[9];
  float* out = (float*)d_out;

  char* ws = (char*)d_ws;
  __bf16* w1f = (__bf16*)(ws + 0);
  __bf16* wqf = (__bf16*)(ws + 294912);
  __bf16* wkf = (__bf16*)(ws + 368640);
  __bf16* wvf = (__bf16*)(ws + 442368);
  __bf16* w2f = (__bf16*)(ws + 516096);
  float* cq = (float*)(ws + 811008);
  float* sq = cq + 6144;
  float* ck = sq + 6144;
  float* sk = ck + 6144;

  hipLaunchKernelGGL(prep_weights, dim3(1584), dim3(256), 0, stream,
                     W1, WQ, WK, WV, W2, w1f, wqf, wkf, wvf, w2f);
  hipLaunchKernelGGL(prep_tables, dim3(12), dim3(256), 0, stream, cq, sq, ck, sk);
  hipLaunchKernelGGL(retnet_main, dim3(1568), dim3(256), 0, stream,
                     x, b1, b2, lng, lnb, w1f, wqf, wkf, wvf, w2f,
                     cq, sq, ck, sk, out);
}